// Round 10
// baseline (246.654 us; speedup 1.0000x reference)
//
#include <hip/hip_runtime.h>

// GCN 2-layer: N=100000, E=3200000, IN=8, HID=64, OUT=1.
// Round 10: R9 pipeline (bucket scatter -> per-bucket counting sort ->
// zero-atomic thread-per-node compute), re-chunked for occupancy.
//  R9's kA_scatter: 55us, occupancy 24% (250 blocks x 1024 thr = ~1 block/CU,
//  16/32 waves), latency-bound on col-load -> LDS-atomic -> scattered-store.
//  Now: 1000 chunks x 3200 edges, 256-thr blocks, 8KB LDS -> ~8 blocks/CU.
//  Hierarchical chunk scan: 8 groups of 125 chunks (scan1 in-group 16K thr,
//  scan2+bucket-base scan fused in one block). k_xw fused into sortdeg.

#define N_    100000
#define E_    3200000
#define BK    2048        // buckets = col >> 6 (64 nodes/bucket)
#define NBUCK 1563        // ceil(N_/64)
#define CA    1000        // phase-A edge chunks
#define CSA   3200        // E_/CA
#define GG    8           // chunk groups
#define GCH   125         // chunks per group
#define CAP   3072        // per-bucket LDS edge capacity (mean 2048, sd ~45)
#define NBLK  391         // ceil(N_/256)

// ---- A1: per-(chunk,bucket) histogram. countsA chunk-major [c][b].
__global__ void kA_hist(const int* __restrict__ col, int* __restrict__ countsA) {
    __shared__ int bins[BK];
    int c = blockIdx.x, t = threadIdx.x;
    for (int i = t; i < BK; i += 256) bins[i] = 0;
    __syncthreads();
    const int* cp = col + c * CSA;
    #pragma unroll
    for (int it = 0; it < 3; it++) {
        int e = t + it * 1024;
        int v0 = cp[e], v1 = cp[e + 256], v2 = cp[e + 512], v3 = cp[e + 768];
        atomicAdd(&bins[v0 >> 6], 1);
        atomicAdd(&bins[v1 >> 6], 1);
        atomicAdd(&bins[v2 >> 6], 1);
        atomicAdd(&bins[v3 >> 6], 1);
    }
    if (t < 128) atomicAdd(&bins[cp[3072 + t] >> 6], 1);
    __syncthreads();
    int* outp = countsA + (size_t)c * BK;
    for (int i = t; i < BK; i += 256) outp[i] = bins[i];
}

// ---- A2a: within-group exclusive prefix across chunks.
//   thread (g,b): countsA[c][b] <- prefix within group; grptot[g][b] = total
__global__ void kA_scan1(int* __restrict__ countsA, int* __restrict__ grptot) {
    int tid = blockIdx.x * 256 + threadIdx.x;   // 16384 threads
    int g = tid >> 11;
    int b = tid & (BK - 1);
    int c0 = g * GCH;
    int run = 0;
    #pragma unroll 5
    for (int k = 0; k < GCH; k++) {
        size_t idx = (size_t)(c0 + k) * BK + b;
        int v = countsA[idx];
        countsA[idx] = run;
        run += v;
    }
    grptot[g * BK + b] = run;
}

// ---- A2b (one block, 1024 thr): scan grptot across groups per bucket,
//   then exclusive scan of bucket totals -> baseB; fold baseB into grptot
//   so scatter needs only two adds.
__global__ void kA_scan2B(int* __restrict__ grptot, int* __restrict__ baseB) {
    __shared__ int sm[1024];
    int t = threadIdx.x;
    int tot0, tot1;
    {   // bucket 2t
        int b = 2 * t, run = 0;
        #pragma unroll
        for (int g = 0; g < GG; g++) {
            int idx = g * BK + b;
            int v = grptot[idx];
            grptot[idx] = run;
            run += v;
        }
        tot0 = run;
    }
    {   // bucket 2t+1
        int b = 2 * t + 1, run = 0;
        #pragma unroll
        for (int g = 0; g < GG; g++) {
            int idx = g * BK + b;
            int v = grptot[idx];
            grptot[idx] = run;
            run += v;
        }
        tot1 = run;
    }
    int pair = tot0 + tot1;
    sm[t] = pair;
    __syncthreads();
    for (int off = 1; off < 1024; off <<= 1) {
        int add = (t >= off) ? sm[t - off] : 0;
        __syncthreads();
        sm[t] += add;
        __syncthreads();
    }
    int excl = sm[t] - pair;
    baseB[2 * t]     = excl;
    baseB[2 * t + 1] = excl + tot0;
    if (t == 1023) baseB[BK] = sm[1023];
    // fold baseB into grptot: grptot[g][b] += baseB[b]
    #pragma unroll
    for (int g = 0; g < GG; g++) {
        grptot[g * BK + 2 * t]     += excl;
        grptot[g * BK + 2 * t + 1] += excl + tot0;
    }
}

// ---- A3: scatter packed records {row|lc<<17, w} into bucket segments
__global__ void kA_scatter(const int* __restrict__ row, const int* __restrict__ col,
                           const float* __restrict__ w,
                           const int* __restrict__ countsA, const int* __restrict__ grptot,
                           int2* __restrict__ brec) {
    __shared__ int curs[BK];
    int c = blockIdx.x, t = threadIdx.x;
    int g = c / GCH;
    const int* pc = countsA + (size_t)c * BK;
    const int* go = grptot + g * BK;
    for (int i = t; i < BK; i += 256) curs[i] = go[i] + pc[i];
    __syncthreads();
    const int* cp = col + c * CSA;
    const int* rp = row + c * CSA;
    const float* wp = w + c * CSA;
    #pragma unroll
    for (int it = 0; it < 3; it++) {
        int e = t + it * 1024;
        int v0 = cp[e], v1 = cp[e + 256], v2 = cp[e + 512], v3 = cp[e + 768];
        int r0 = rp[e], r1 = rp[e + 256], r2 = rp[e + 512], r3 = rp[e + 768];
        float w0 = wp[e], w1 = wp[e + 256], w2 = wp[e + 512], w3 = wp[e + 768];
        int p0 = atomicAdd(&curs[v0 >> 6], 1);
        brec[p0] = make_int2(r0 | ((v0 & 63) << 17), __float_as_int(w0));
        int p1 = atomicAdd(&curs[v1 >> 6], 1);
        brec[p1] = make_int2(r1 | ((v1 & 63) << 17), __float_as_int(w1));
        int p2 = atomicAdd(&curs[v2 >> 6], 1);
        brec[p2] = make_int2(r2 | ((v2 & 63) << 17), __float_as_int(w2));
        int p3 = atomicAdd(&curs[v3 >> 6], 1);
        brec[p3] = make_int2(r3 | ((v3 & 63) << 17), __float_as_int(w3));
    }
    if (t < 128) {
        int e2 = 3072 + t;
        int v = cp[e2];
        int pos = atomicAdd(&curs[v >> 6], 1);
        brec[pos] = make_int2(rp[e2] | ((v & 63) << 17), __float_as_int(wp[e2]));
    }
}

// ---- B-sort: per-bucket counting sort by local col -> per-node CSR + deg +
//   dinv + xw (xw[n] = dinv[n]*x[n]). brec written back sorted {row, w}.
__global__ void kB_sortdeg(const int* __restrict__ baseB, int2* __restrict__ brec,
                           const float* __restrict__ x,
                           float* __restrict__ dinv, float* __restrict__ xw,
                           int* __restrict__ nodeptr) {
    __shared__ int2 raw[CAP];
    __shared__ int2 sorted[CAP];
    __shared__ int  h[4 * 64];
    __shared__ int  nb[65];
    int b = blockIdx.x, t = threadIdx.x;
    int wid = t >> 6;
    int st = baseB[b];
    int cnt = baseB[b + 1] - st;
    if (cnt > CAP) cnt = CAP;      // statistically impossible; guard
    h[t] = 0;
    __syncthreads();
    int i = t;
    for (; i + 768 < cnt; i += 1024) {
        int2 q0 = brec[st + i], q1 = brec[st + i + 256];
        int2 q2 = brec[st + i + 512], q3 = brec[st + i + 768];
        raw[i] = q0; raw[i + 256] = q1; raw[i + 512] = q2; raw[i + 768] = q3;
        atomicAdd(&h[(wid << 6) + (q0.x >> 17)], 1);
        atomicAdd(&h[(wid << 6) + (q1.x >> 17)], 1);
        atomicAdd(&h[(wid << 6) + (q2.x >> 17)], 1);
        atomicAdd(&h[(wid << 6) + (q3.x >> 17)], 1);
    }
    for (; i < cnt; i += 256) {
        int2 q = brec[st + i];
        raw[i] = q;
        atomicAdd(&h[(wid << 6) + (q.x >> 17)], 1);
    }
    __syncthreads();
    if (t < 64) {
        int off = 0;
        #pragma unroll
        for (int w2 = 0; w2 < 4; w2++) {
            int cc = h[(w2 << 6) + t];
            h[(w2 << 6) + t] = off;
            off += cc;
        }
        int val = off;
        #pragma unroll
        for (int d = 1; d < 64; d <<= 1) {
            int u = __shfl_up(val, d);
            if (t >= d) val += u;
        }
        nb[t] = val - off;
        if (t == 63) nb[64] = val;
    }
    __syncthreads();
    if (t < 64) {
        int e2 = nb[t];
        #pragma unroll
        for (int w2 = 0; w2 < 4; w2++) h[(w2 << 6) + t] += e2;
    }
    __syncthreads();
    for (int j = t; j < cnt; j += 256) {
        int2 q = raw[j];
        int lc = q.x >> 17;
        int pos = atomicAdd(&h[(wid << 6) + lc], 1);
        sorted[pos] = make_int2(q.x & 0x1FFFF, q.y);
    }
    __syncthreads();
    if (t < 64) {
        int n = (b << 6) + t;
        float d = 0.0f;
        int e0 = nb[t], e1 = nb[t + 1];
        for (int k = e0; k < e1; k++) d += __int_as_float(sorted[k].y);
        if (n < N_) {
            float di = rsqrtf(d + 1.0f);
            dinv[n] = di;
            nodeptr[n] = st + e0;
            const float4* xi = (const float4*)(x + (size_t)n * 8);
            float4 xa = xi[0], xb = xi[1];
            float4* o = (float4*)(xw + (size_t)n * 8);
            o[0] = make_float4(di * xa.x, di * xa.y, di * xa.z, di * xa.w);
            o[1] = make_float4(di * xb.x, di * xb.y, di * xb.z, di * xb.w);
        }
        if (b == NBUCK - 1 && t == 0) nodeptr[N_] = E_;
    }
    __syncthreads();
    i = t;
    for (; i + 768 < cnt; i += 1024) {
        brec[st + i]       = sorted[i];
        brec[st + i + 256] = sorted[i + 256];
        brec[st + i + 512] = sorted[i + 512];
        brec[st + i + 768] = sorted[i + 768];
    }
    for (; i < cnt; i += 256) brec[st + i] = sorted[i];
}

// ---- B2: thread-per-node register aggregation + MLP. Zero atomics.
__global__ void kB2_node(const int* __restrict__ nodeptr, const int2* __restrict__ srec,
                         const float* __restrict__ dinv,
                         const float* __restrict__ xw,
                         const float* __restrict__ W1,
                         const float* __restrict__ b1,
                         const float* __restrict__ W2,
                         float* __restrict__ tv) {
    __shared__ float sW1[8 * 64];
    __shared__ float sb1[64];
    __shared__ float sW2[64];
    int t = threadIdx.x;
    for (int i = t; i < 8 * 64; i += 256) sW1[i] = W1[i];
    if (t < 64) { sb1[t] = b1[t]; sW2[t] = W2[t]; }
    __syncthreads();
    int n = blockIdx.x * 256 + t;
    if (n >= N_) return;
    int st = nodeptr[n], en = nodeptr[n + 1];
    float di = dinv[n];
    const float4* xw4 = (const float4*)xw;
    float4 s0 = xw4[2 * n], s1 = xw4[2 * n + 1];
    float a[8];
    a[0] = s0.x; a[1] = s0.y; a[2] = s0.z; a[3] = s0.w;
    a[4] = s1.x; a[5] = s1.y; a[6] = s1.z; a[7] = s1.w;
    int e = st;
    for (; e + 3 < en; e += 4) {
        int2 q0 = srec[e], q1 = srec[e + 1], q2 = srec[e + 2], q3 = srec[e + 3];
        float4 f0a = xw4[2 * q0.x], f0b = xw4[2 * q0.x + 1];
        float4 f1a = xw4[2 * q1.x], f1b = xw4[2 * q1.x + 1];
        float4 f2a = xw4[2 * q2.x], f2b = xw4[2 * q2.x + 1];
        float4 f3a = xw4[2 * q3.x], f3b = xw4[2 * q3.x + 1];
        float w0 = __int_as_float(q0.y), w1 = __int_as_float(q1.y);
        float w2 = __int_as_float(q2.y), w3 = __int_as_float(q3.y);
        a[0] = fmaf(w0, f0a.x, a[0]); a[1] = fmaf(w0, f0a.y, a[1]);
        a[2] = fmaf(w0, f0a.z, a[2]); a[3] = fmaf(w0, f0a.w, a[3]);
        a[4] = fmaf(w0, f0b.x, a[4]); a[5] = fmaf(w0, f0b.y, a[5]);
        a[6] = fmaf(w0, f0b.z, a[6]); a[7] = fmaf(w0, f0b.w, a[7]);
        a[0] = fmaf(w1, f1a.x, a[0]); a[1] = fmaf(w1, f1a.y, a[1]);
        a[2] = fmaf(w1, f1a.z, a[2]); a[3] = fmaf(w1, f1a.w, a[3]);
        a[4] = fmaf(w1, f1b.x, a[4]); a[5] = fmaf(w1, f1b.y, a[5]);
        a[6] = fmaf(w1, f1b.z, a[6]); a[7] = fmaf(w1, f1b.w, a[7]);
        a[0] = fmaf(w2, f2a.x, a[0]); a[1] = fmaf(w2, f2a.y, a[1]);
        a[2] = fmaf(w2, f2a.z, a[2]); a[3] = fmaf(w2, f2a.w, a[3]);
        a[4] = fmaf(w2, f2b.x, a[4]); a[5] = fmaf(w2, f2b.y, a[5]);
        a[6] = fmaf(w2, f2b.z, a[6]); a[7] = fmaf(w2, f2b.w, a[7]);
        a[0] = fmaf(w3, f3a.x, a[0]); a[1] = fmaf(w3, f3a.y, a[1]);
        a[2] = fmaf(w3, f3a.z, a[2]); a[3] = fmaf(w3, f3a.w, a[3]);
        a[4] = fmaf(w3, f3b.x, a[4]); a[5] = fmaf(w3, f3b.y, a[5]);
        a[6] = fmaf(w3, f3b.z, a[6]); a[7] = fmaf(w3, f3b.w, a[7]);
    }
    for (; e < en; e++) {
        int2 q = srec[e];
        float4 fa = xw4[2 * q.x], fb = xw4[2 * q.x + 1];
        float w0 = __int_as_float(q.y);
        a[0] = fmaf(w0, fa.x, a[0]); a[1] = fmaf(w0, fa.y, a[1]);
        a[2] = fmaf(w0, fa.z, a[2]); a[3] = fmaf(w0, fa.w, a[3]);
        a[4] = fmaf(w0, fb.x, a[4]); a[5] = fmaf(w0, fb.y, a[5]);
        a[6] = fmaf(w0, fb.z, a[6]); a[7] = fmaf(w0, fb.w, a[7]);
    }
    #pragma unroll
    for (int k = 0; k < 8; k++) a[k] *= di;
    float sv = 0.0f;
    #pragma unroll
    for (int j = 0; j < 64; j++) {
        float h = sb1[j];
        #pragma unroll
        for (int k = 0; k < 8; k++) h = fmaf(a[k], sW1[k * 64 + j], h);
        sv = fmaf(fmaxf(h, 0.0f), sW2[j], sv);
    }
    tv[n] = di * sv;
}

// ---- B3: thread-per-node layer-2. out = b2 + dinv[n]*(tv[n] + sum w*tv[r])
__global__ void kB3_node(const int* __restrict__ nodeptr, const int2* __restrict__ srec,
                         const float* __restrict__ dinv,
                         const float* __restrict__ tv,
                         const float* __restrict__ b2,
                         float* __restrict__ out) {
    int n = blockIdx.x * 256 + threadIdx.x;
    if (n >= N_) return;
    int st = nodeptr[n], en = nodeptr[n + 1];
    float acc = tv[n];
    int e = st;
    for (; e + 3 < en; e += 4) {
        int2 q0 = srec[e], q1 = srec[e + 1], q2 = srec[e + 2], q3 = srec[e + 3];
        float t0 = tv[q0.x], t1 = tv[q1.x], t2 = tv[q2.x], t3 = tv[q3.x];
        acc = fmaf(__int_as_float(q0.y), t0, acc);
        acc = fmaf(__int_as_float(q1.y), t1, acc);
        acc = fmaf(__int_as_float(q2.y), t2, acc);
        acc = fmaf(__int_as_float(q3.y), t3, acc);
    }
    for (; e < en; e++) {
        int2 q = srec[e];
        acc = fmaf(__int_as_float(q.y), tv[q.x], acc);
    }
    out[n] = b2[0] + dinv[n] * acc;
}

extern "C" void kernel_launch(void* const* d_in, const int* in_sizes, int n_in,
                              void* d_out, int out_size, void* d_ws, size_t ws_size,
                              hipStream_t stream) {
    const float* x  = (const float*)d_in[0];
    const int*   ei = (const int*)d_in[1];    // [2, E] int32
    const float* w  = (const float*)d_in[2];
    const float* W1 = (const float*)d_in[3];
    const float* b1 = (const float*)d_in[4];
    const float* W2 = (const float*)d_in[5];
    const float* b2 = (const float*)d_in[6];
    float* out = (float*)d_out;

    const int* row = ei;
    const int* col = ei + E_;

    // ws (ints): countsA[CA*BK]=2048000 | grptot[GG*BK]=16384 |
    //   baseB[2049 pad 2560] | nodeptr[100352] | dinv[N] | xw[8N] | tv[N] |
    //   brec[E] int2                                   ~38.3 MB
    int*   wsI     = (int*)d_ws;
    int*   countsA = wsI;
    int*   grptot  = wsI + (size_t)CA * BK;          // 2048000
    int*   baseB   = grptot + GG * BK;               // +16384
    int*   nodeptr = baseB + 2560;
    float* dinv    = (float*)(nodeptr + 100352);
    float* xw      = dinv + N_;
    float* tv      = xw + (size_t)8 * N_;
    int2*  brec    = (int2*)(tv + N_);

    kA_hist   <<<CA, 256, 0, stream>>>(col, countsA);
    kA_scan1  <<<64, 256, 0, stream>>>(countsA, grptot);
    kA_scan2B <<<1, 1024, 0, stream>>>(grptot, baseB);
    kA_scatter<<<CA, 256, 0, stream>>>(row, col, w, countsA, grptot, brec);
    kB_sortdeg<<<NBUCK, 256, 0, stream>>>(baseB, brec, x, dinv, xw, nodeptr);
    kB2_node  <<<NBLK, 256, 0, stream>>>(nodeptr, brec, dinv, xw, W1, b1, W2, tv);
    kB3_node  <<<NBLK, 256, 0, stream>>>(nodeptr, brec, dinv, tv, b2, out);
}